// Round 5
// baseline (359.626 us; speedup 1.0000x reference)
//
#include <hip/hip_runtime.h>

// DeformConv fused pipeline v4, MI355X (gfx950).
// v4: A-fragments direct from L2 (no A LDS), single barrier per K-tile,
//     bilinear meta computed inline in k3 (k2b deleted), b_off folded into k1,
//     k1 same single-barrier dbuf pipeline.

#define BATCH 8
#define CIN   256
#define COUT  256
#define HH    56
#define WW    56
#define HW    3136
#define NPIX  25088
#define KTAP  9
#define KG    2304
#define NKT   36

typedef unsigned short ushortT;
typedef _Float16 f16x8 __attribute__((ext_vector_type(8)));
typedef float f32x4 __attribute__((ext_vector_type(4)));

__device__ __forceinline__ f16x8 lds_ldh8(const ushortT* p) {
    uint4 u = *(const uint4*)p;
    return __builtin_bit_cast(f16x8, u);
}
__device__ __forceinline__ unsigned packh2(float v0, float v1) {
    _Float16 h0 = (_Float16)v0, h1 = (_Float16)v1;
    return (unsigned)__builtin_bit_cast(unsigned short, h0)
         | ((unsigned)__builtin_bit_cast(unsigned short, h1) << 16);
}

// ---------------------------------------------------------------------------
// K0: transpose x NCHW -> xt NHWC (fp32), XCD-chunked (image per XCD).
// ---------------------------------------------------------------------------
__global__ __launch_bounds__(256) void k0_transpose(
    const float* __restrict__ x, float* __restrict__ xt)
{
    __shared__ float t[64][65];
    const int bid = (blockIdx.x & 7) * 196 + (blockIdx.x >> 3);   // 1568 = 8*196
    const int b   = bid / 196;
    const int r   = bid % 196;
    const int hw0 = (r >> 2) * 64;
    const int c0  = (r & 3) * 64;
    const int tid = threadIdx.x;

    {
        const int c_l = tid >> 2, ch = (tid & 3) * 16;
        const float* src = x + ((size_t)(b*CIN + c0 + c_l))*HW + hw0 + ch;
        float4 v0 = *(const float4*)(src + 0);
        float4 v1 = *(const float4*)(src + 4);
        float4 v2 = *(const float4*)(src + 8);
        float4 v3 = *(const float4*)(src + 12);
        *(float4*)&t[c_l][ch + 0]  = v0;
        *(float4*)&t[c_l][ch + 4]  = v1;
        *(float4*)&t[c_l][ch + 8]  = v2;
        *(float4*)&t[c_l][ch + 12] = v3;
    }
    __syncthreads();
    {
        const int hw_l = tid >> 2, cc = (tid & 3) * 16;
        float* dst = xt + ((size_t)(b*HW + hw0 + hw_l))*CIN + c0 + cc;
        #pragma unroll
        for (int q = 0; q < 4; ++q) {
            float4 o;
            o.x = t[cc + q*4 + 0][hw_l];
            o.y = t[cc + q*4 + 1][hw_l];
            o.z = t[cc + q*4 + 2][hw_l];
            o.w = t[cc + q*4 + 3][hw_l];
            *(float4*)(dst + q*4) = o;
        }
    }
}

// ---------------------------------------------------------------------------
// K2a: weight prep (fp16, tap-major kg = k*256+i, LINEAR layout) + BN coeffs.
//  Ah  [kt][m 0..255][kk 0..63], A0h [ktg][m 0..31][kk 0..63]
// ---------------------------------------------------------------------------
__global__ void k2a_prep(const float* __restrict__ wconv, const float* __restrict__ woff,
                         const float* __restrict__ g, const float* __restrict__ be,
                         const float* __restrict__ rm, const float* __restrict__ rv,
                         ushortT* __restrict__ Ah, ushortT* __restrict__ A0h,
                         float* __restrict__ scale, float* __restrict__ shift)
{
    int id = blockIdx.x*256 + threadIdx.x;
    if (id < COUT*KG) {
        int m = id / KG, kg = id % KG;
        int k = kg >> 8, i = kg & 255;
        float f = wconv[(m*CIN + i)*9 + k];
        int kt = kg >> 6, kk = kg & 63;
        _Float16 h = (_Float16)f;
        Ah[kt*16384 + m*64 + kk] = __builtin_bit_cast(unsigned short, h);
    } else if (id < COUT*KG + 32*KG) {
        int id2 = id - COUT*KG;
        int m = id2 / KG, kg = id2 % KG;
        int k = kg >> 8, i = kg & 255;
        float f = (m < 18) ? woff[(m*CIN + i)*9 + k] : 0.f;
        int kt = kg >> 6, kk = kg & 63;
        _Float16 h = (_Float16)f;
        A0h[kt*2048 + m*64 + kk] = __builtin_bit_cast(unsigned short, h);
    } else if (id < COUT*KG + 32*KG + 256) {
        int t = id - (COUT*KG + 32*KG);
        float inv = g[t] / sqrtf(rv[t] + 1e-5f);
        scale[t] = inv;
        shift[t] = be[t] - rm[t]*inv;
    }
}

// ---------------------------------------------------------------------------
// K1: offset conv thin MFMA GEMM, K-split x4, atomicAdd partials (+bias on ks0).
// grid 1568 = 8 xcd * (49 tiles * 4 ksplit); 256 thr (4 waves), BN=64, BK=64.
// Single barrier per iter: A0 frags from global regs, B im2col double-buffered.
// ---------------------------------------------------------------------------
__global__ __launch_bounds__(256, 4) void k1_offmfma(
    const float* __restrict__ xt, const ushortT* __restrict__ A0h_g,
    const float* __restrict__ b_off, float* __restrict__ off)
{
    __shared__ __align__(16) ushortT Bh[2][64*64];   // 2 x 8 KB

    const int tid = threadIdx.x;
    const int x8 = blockIdx.x & 7;        // xcd == image
    const int j  = blockIdx.x >> 3;       // [0,196)
    const int tile = x8*49 + (j % 49);
    const int ks = j / 49;                // K-split slice [0,4)
    const int bn0 = tile * 64;

    const int wv = tid >> 6, lane = tid & 63;
    const int l16 = lane & 15, lq = lane >> 4;
    const int px_l = tid >> 2, g2 = tid & 3;

    const int np = bn0 + px_l;
    const int hw = np - x8*HW;
    const int h = hw / WW, w = hw % WW;

    f32x4 acc[2] = {};
    float4 iv0, iv1, iv2, iv3;

    #define K1_IM2COL(ktg_) do {                                               \
        const int tap_ = (ktg_) >> 2, ic_ = (ktg_) & 3;                        \
        const int ky_ = tap_ / 3 - 1, kx_ = tap_ % 3 - 1;                      \
        const int hs_ = h + ky_, ws_ = w + kx_;                                \
        const bool valid_ = (hs_ >= 0 && hs_ < HH && ws_ >= 0 && ws_ < WW);    \
        const float* p_ = xt + ((size_t)(np + ky_*WW + kx_))*CIN + ic_*64 + g2*16; \
        if (valid_) {                                                          \
            iv0 = *(const float4*)(p_ + 0);  iv1 = *(const float4*)(p_ + 4);   \
            iv2 = *(const float4*)(p_ + 8);  iv3 = *(const float4*)(p_ + 12);  \
        } else {                                                               \
            iv0 = iv1 = iv2 = iv3 = make_float4(0.f, 0.f, 0.f, 0.f);           \
        }                                                                      \
    } while (0)

    #define K1_PACK(buf_) do {                                                 \
        uint4 h0_, h1_;                                                        \
        h0_.x = packh2(iv0.x, iv0.y); h0_.y = packh2(iv0.z, iv0.w);            \
        h0_.z = packh2(iv1.x, iv1.y); h0_.w = packh2(iv1.z, iv1.w);            \
        h1_.x = packh2(iv2.x, iv2.y); h1_.y = packh2(iv2.z, iv2.w);            \
        h1_.z = packh2(iv3.x, iv3.y); h1_.w = packh2(iv3.z, iv3.w);            \
        const int base_ = g2 * 16;                                             \
        *(uint4*)&Bh[buf_][px_l*64 + ((base_ + 0) ^ ((px_l & 7) << 3))] = h0_; \
        *(uint4*)&Bh[buf_][px_l*64 + ((base_ + 8) ^ ((px_l & 7) << 3))] = h1_; \
    } while (0)

    // prologue
    K1_IM2COL(ks*9);
    K1_PACK(0);
    asm volatile("s_waitcnt lgkmcnt(0)" ::: "memory");
    __builtin_amdgcn_s_barrier();
    __builtin_amdgcn_sched_barrier(0);

    for (int t = 0; t < 9; ++t) {
        const int ktg = ks*9 + t;
        const int cur = t & 1;
        // A0 frags direct from global (L2): 2 mf x 2 ks
        f16x8 a00, a01, a10, a11;
        {
            const ushortT* ap = A0h_g + ktg*2048 + l16*64 + lq*8;
            a00 = *(const f16x8*)(ap + 0);
            a01 = *(const f16x8*)(ap + 32);
            a10 = *(const f16x8*)(ap + 16*64 + 0);
            a11 = *(const f16x8*)(ap + 16*64 + 32);
        }
        if (t < 8) K1_IM2COL(ktg + 1);
        {
            const int n = wv*16 + l16;
            const int kk0 = lq*8;
            f16x8 b0 = lds_ldh8(&Bh[cur][n*64 + ((kk0     ) ^ ((n & 7) << 3))]);
            f16x8 b1 = lds_ldh8(&Bh[cur][n*64 + ((kk0 + 32) ^ ((n & 7) << 3))]);
            acc[0] = __builtin_amdgcn_mfma_f32_16x16x32_f16(a00, b0, acc[0], 0, 0, 0);
            acc[1] = __builtin_amdgcn_mfma_f32_16x16x32_f16(a10, b0, acc[1], 0, 0, 0);
            acc[0] = __builtin_amdgcn_mfma_f32_16x16x32_f16(a01, b1, acc[0], 0, 0, 0);
            acc[1] = __builtin_amdgcn_mfma_f32_16x16x32_f16(a11, b1, acc[1], 0, 0, 0);
        }
        if (t < 8) K1_PACK(cur ^ 1);
        asm volatile("s_waitcnt lgkmcnt(0)" ::: "memory");
        __builtin_amdgcn_s_barrier();
        __builtin_amdgcn_sched_barrier(0);
    }

    const int n = bn0 + wv*16 + l16;
    const int hw2 = n - x8*HW;
    #pragma unroll
    for (int mf = 0; mf < 2; ++mf) {
        #pragma unroll
        for (int r = 0; r < 4; ++r) {
            const int m = mf*16 + lq*4 + r;
            if (m < 18) {
                float v = acc[mf][r];
                if (ks == 0) v += b_off[m];
                atomicAdd(&off[((size_t)x8*18 + m)*HW + hw2], v);
            }
        }
    }
    #undef K1_IM2COL
    #undef K1_PACK
}

// ---------------------------------------------------------------------------
// K3: fused inline-meta gather + fp16 MFMA (A from L2 regs / B hi+lo LDS dbuf)
//     + BN + ReLU. grid 392 = 8 xcd * 49; 512 thr; BM=256, BN=64, BK=64.
//     ONE barrier per K-tile.
// ---------------------------------------------------------------------------
__global__ __launch_bounds__(512, 4) void k3_main(
    const float* __restrict__ xt, const float* __restrict__ off_g,
    const float* __restrict__ b_off_g, const ushortT* __restrict__ Ah_g,
    const float* __restrict__ scale_g, const float* __restrict__ shift_g,
    float* __restrict__ out)
{
    __shared__ __align__(16) ushortT Bh_t[2][64*64];   // 2 x 8 KB
    __shared__ __align__(16) ushortT Bl_t[2][64*64];   // 2 x 8 KB
    __shared__ float s_scale[256], s_shift[256];

    const int tid = threadIdx.x;
    const int bimg = blockIdx.x & 7;                  // xcd == image
    const int lt   = blockIdx.x >> 3;                 // [0,49)
    const int bn0  = (bimg*49 + lt) * 64;
    if (tid < 256) { s_scale[tid] = scale_g[tid]; s_shift[tid] = shift_g[tid]; }

    const int wv = tid >> 6, lane = tid & 63;
    const int l16 = lane & 15, lq = lane >> 4;
    const int mbase = (wv >> 1) * 64;
    const int nbase = (wv & 1) * 32;
    const int px_l = tid >> 3, g = tid & 7;
    const int hwp  = lt*64 + px_l;                    // pixel within image
    const int hp   = hwp / WW, wp = hwp % WW;

    int   mi[4];
    float mwv[4];
    f32x4 Gc[4][2];
    f32x4 acc[4][2] = {};

    // inline bilinear meta for tap_ (replaces the old k2b kernel)
    #define META(tap_) do {                                                    \
        float dy_ = off_g[((size_t)bimg*18 + 2*(tap_)    )*HW + hwp] + b_off_g[2*(tap_)]; \
        float dx_ = off_g[((size_t)bimg*18 + 2*(tap_) + 1)*HW + hwp] + b_off_g[2*(tap_) + 1]; \
        float py_ = (float)(hp - 1 + ((tap_) / 3)) + dy_;                      \
        float px_ = (float)(wp - 1 + ((tap_) % 3)) + dx_;                      \
        py_ = fminf(fmaxf(py_, -30000.f), 30000.f);                            \
        px_ = fminf(fmaxf(px_, -30000.f), 30000.f);                            \
        float y0f_ = floorf(py_), x0f_ = floorf(px_);                          \
        int y0_ = (int)y0f_, x0_ = (int)x0f_;                                  \
        float ly_ = py_ - y0f_, lx_ = px_ - x0f_;                              \
        float wy0_ = 1.f - ly_, wx0_ = 1.f - lx_;                              \
        _Pragma("unroll")                                                      \
        for (int c_ = 0; c_ < 4; ++c_) {                                       \
            int yi_ = y0_ + (c_ >> 1), xi_ = x0_ + (c_ & 1);                   \
            bool v_ = (yi_ >= 0) && (yi_ < HH) && (xi_ >= 0) && (xi_ < WW);    \
            int yc_ = min(max(yi_, 0), HH-1), xc_ = min(max(xi_, 0), WW-1);    \
            mi[c_] = (bimg*HW + yc_*WW + xc_)*CIN;                             \
            float wy_ = (c_ >> 1) ? ly_ : wy0_;                                \
            float wx_ = (c_ & 1) ? lx_ : wx0_;                                 \
            mwv[c_] = v_ ? wy_*wx_ : 0.f;                                      \
        }                                                                      \
    } while (0)

    #define ISSUE_GATHER(j_) do {                                              \
        const float* base_ = xt + ((j_) & 3)*64 + g*8;                         \
        _Pragma("unroll")                                                      \
        for (int c_ = 0; c_ < 4; ++c_) {                                       \
            const float* p_ = base_ + mi[c_];                                  \
            Gc[c_][0] = *(const f32x4*)p_;                                     \
            Gc[c_][1] = *(const f32x4*)(p_ + 4);                               \
        }                                                                      \
    } while (0)

    #define BLEND_WRITE(buf_) do {                                             \
        float v_[8];                                                           \
        _Pragma("unroll")                                                      \
        for (int q_ = 0; q_ < 4; ++q_) {                                       \
            v_[q_]   = mwv[0]*Gc[0][0][q_] + mwv[1]*Gc[1][0][q_]               \
                     + mwv[2]*Gc[2][0][q_] + mwv[3]*Gc[3][0][q_];              \
            v_[4+q_] = mwv[0]*Gc[0][1][q_] + mwv[1]*Gc[1][1][q_]               \
                     + mwv[2]*Gc[2][1][q_] + mwv[3]*Gc[3][1][q_];              \
        }                                                                      \
        uint4 hi_, lo_;                                                        \
        float r_[8];                                                           \
        _Pragma("unroll")                                                      \
        for (int q_ = 0; q_ < 8; ++q_) {                                       \
            _Float16 hh_ = (_Float16)v_[q_];                                   \
            r_[q_] = v_[q_] - (float)hh_;                                      \
        }                                                                      \
        hi_.x = packh2(v_[0], v_[1]); hi_.y = packh2(v_[2], v_[3]);            \
        hi_.z = packh2(v_[4], v_[5]); hi_.w = packh2(v_[6], v_[7]);            \
        lo_.x = packh2(r_[0], r_[1]); lo_.y = packh2(r_[2], r_[3]);            \
        lo_.z = packh2(r_[4], r_[5]); lo_.w = packh2(r_[6], r_[7]);            \
        const int idx_ = px_l*64 + ((g*8) ^ ((px_l & 7) << 3));                \
        *(uint4*)&Bh_t[buf_][idx_] = hi_;                                      \
        *(uint4*)&Bl_t[buf_][idx_] = lo_;                                      \
    } while (0)

    #define MFMA_PHASE(cur_) do {                                              \
        __builtin_amdgcn_s_setprio(1);                                         \
        _Pragma("unroll")                                                      \
        for (int ks_ = 0; ks_ < 2; ++ks_) {                                    \
            const int kk0_ = ks_*32 + lq*8;                                    \
            f16x8 bh_[2], bl_[2];                                              \
            _Pragma("unroll")                                                  \
            for (int nf_ = 0; nf_ < 2; ++nf_) {                                \
                const int n_ = nbase + nf_*16 + l16;                           \
                const int ix_ = n_*64 + (kk0_ ^ ((n_ & 7) << 3));              \
                bh_[nf_] = lds_ldh8(&Bh_t[cur_][ix_]);                         \
                bl_[nf_] = lds_ldh8(&Bl_t[cur_][ix_]);                         \
            }                                                                  \
            _Pragma("unroll")                                                  \
            for (int mf_ = 0; mf_ < 4; ++mf_) {                                \
                _Pragma("unroll")                                              \
                for (int nf_ = 0; nf_ < 2; ++nf_) {                            \
                    acc[mf_][nf_] = __builtin_amdgcn_mfma_f32_16x16x32_f16(a_[mf_][ks_], bh_[nf_], acc[mf_][nf_], 0, 0, 0); \
                    acc[mf_][nf_] = __builtin_amdgcn_mfma_f32_16x16x32_f16(a_[mf_][ks_], bl_[nf_], acc[mf_][nf_], 0, 0, 0); \
                }                                                              \
            }                                                                  \
        }                                                                      \
        __builtin_amdgcn_s_setprio(0);                                         \
    } while (0)

    // ---- prologue: tile 0 ----
    META(0);
    ISSUE_GATHER(0);
    BLEND_WRITE(0);
    asm volatile("s_waitcnt lgkmcnt(0)" ::: "memory");
    __builtin_amdgcn_s_barrier();
    __builtin_amdgcn_sched_barrier(0);

    for (int kt = 0; kt < NKT; ++kt) {
        const int cur = kt & 1;
        // A frags direct from global (L2-resident, linear layout)
        f16x8 a_[4][2];
        {
            const ushortT* ap = Ah_g + (size_t)kt*16384 + (mbase + l16)*64 + lq*8;
            #pragma unroll
            for (int mf_ = 0; mf_ < 4; ++mf_) {
                a_[mf_][0] = *(const f16x8*)(ap + mf_*1024);
                a_[mf_][1] = *(const f16x8*)(ap + mf_*1024 + 32);
            }
        }
        if (kt + 1 < NKT) {
            if (((kt + 1) & 3) == 0) META((kt + 1) >> 2);
            ISSUE_GATHER(kt + 1);
        }
        MFMA_PHASE(cur);
        if (kt + 1 < NKT) BLEND_WRITE(cur ^ 1);
        asm volatile("s_waitcnt lgkmcnt(0)" ::: "memory");
        __builtin_amdgcn_s_barrier();
        __builtin_amdgcn_sched_barrier(0);
    }

    // ---- epilogue: BN + ReLU + store ----
    const int hwb = lt * 64;
    #pragma unroll
    for (int mf = 0; mf < 4; ++mf) {
        #pragma unroll
        for (int nf = 0; nf < 2; ++nf) {
            const int hwloc = hwb + nbase + nf*16 + l16;
            const int m0 = mbase + mf*16 + lq*4;
            float* op = out + ((size_t)bimg*COUT + m0)*HW + hwloc;
            const f32x4 v = acc[mf][nf];
            #pragma unroll
            for (int r = 0; r < 4; ++r) {
                float val = fmaxf(v[r]*s_scale[m0 + r] + s_shift[m0 + r], 0.f);
                op[(size_t)r*HW] = val;
            }
        }
    }
    #undef META
    #undef ISSUE_GATHER
    #undef BLEND_WRITE
    #undef MFMA_PHASE
}

// ---------------------------------------------------------------------------
extern "C" void kernel_launch(void* const* d_in, const int* in_sizes, int n_in,
                              void* d_out, int out_size, void* d_ws, size_t ws_size,
                              hipStream_t stream)
{
    const float* x      = (const float*)d_in[0];
    const float* w_off  = (const float*)d_in[1];
    const float* b_off  = (const float*)d_in[2];
    const float* w_conv = (const float*)d_in[3];
    const float* gamma  = (const float*)d_in[4];
    const float* beta   = (const float*)d_in[5];
    const float* rmean  = (const float*)d_in[6];
    const float* rvar   = (const float*)d_in[7];
    float* out = (float*)d_out;
    char* ws = (char*)d_ws;

    // workspace layout (bytes), total ~28.8 MB
    float*   xt    = (float*)(ws + 0);           // 25690112 B
    float*   off   = (float*)(ws + 25690112);    //  1806336 B (atomic-summed)
    ushortT* Ah    = (ushortT*)(ws + 27496448);  //  1179648 B
    ushortT* A0h   = (ushortT*)(ws + 28676096);  //   147456 B
    float*   scale = (float*)(ws + 28823552);    //     1024 B
    float*   shift = (float*)(ws + 28824576);    //     1024 B

    hipMemsetAsync(off, 0, 1806336, stream);     // k1 accumulates atomically
    hipLaunchKernelGGL(k0_transpose, dim3(1568), dim3(256), 0, stream, x, xt);
    hipLaunchKernelGGL(k2a_prep, dim3((COUT*KG + 32*KG + 256 + 255)/256), dim3(256), 0, stream,
                       w_conv, w_off, gamma, beta, rmean, rvar, Ah, A0h, scale, shift);
    hipLaunchKernelGGL(k1_offmfma, dim3(1568), dim3(256), 0, stream, xt, A0h, b_off, off);
    hipLaunchKernelGGL(k3_main, dim3(392), dim3(512), 0, stream,
                       xt, off, b_off, Ah, scale, shift, out);
}

// Round 6
// 214.404 us; speedup vs baseline: 1.6773x; 1.6773x over previous
//
#include <hip/hip_runtime.h>

// DeformConv fused pipeline v5, MI355X (gfx950).
// v5: revert k3 to v3.1 async-A pipeline (spill-free, prefetched);
//     k1 un-split (no atomics/memset, bias folded); k0+k2a+BN fused into kA;
//     3 kernels total. Inline bilinear META kept (single bias-add, in k1 only).

#define BATCH 8
#define CIN   256
#define COUT  256
#define HH    56
#define WW    56
#define HW    3136
#define NPIX  25088
#define KTAP  9
#define KG    2304
#define NKT   36

typedef unsigned short ushortT;
typedef _Float16 f16x8 __attribute__((ext_vector_type(8)));
typedef float f32x4 __attribute__((ext_vector_type(4)));

__device__ __forceinline__ f16x8 lds_ldh8(const ushortT* p) {
    uint4 u = *(const uint4*)p;
    return __builtin_bit_cast(f16x8, u);
}
__device__ __forceinline__ unsigned packh2(float v0, float v1) {
    _Float16 h0 = (_Float16)v0, h1 = (_Float16)v1;
    return (unsigned)__builtin_bit_cast(unsigned short, h0)
         | ((unsigned)__builtin_bit_cast(unsigned short, h1) << 16);
}

#define KA_NT 1568                      // transpose blocks
#define KA_NW 2594                      // weight/bn blocks: ceil(663808/256)

// ---------------------------------------------------------------------------
// kA: fused [x NCHW->NHWC transpose] + [weight fp16 prep, swizzle baked] + [BN].
// ---------------------------------------------------------------------------
__global__ __launch_bounds__(256) void kA_prep(
    const float* __restrict__ x, float* __restrict__ xt,
    const float* __restrict__ wconv, const float* __restrict__ woff,
    const float* __restrict__ g, const float* __restrict__ be,
    const float* __restrict__ rm, const float* __restrict__ rv,
    ushortT* __restrict__ Ah, ushortT* __restrict__ A0h,
    float* __restrict__ scale, float* __restrict__ shift)
{
    __shared__ float t[64][65];
    const int tid = threadIdx.x;
    if (blockIdx.x < KA_NT) {
        const int bid = (blockIdx.x & 7) * 196 + (blockIdx.x >> 3);
        const int b   = bid / 196;
        const int r   = bid % 196;
        const int hw0 = (r >> 2) * 64;
        const int c0  = (r & 3) * 64;
        {
            const int c_l = tid >> 2, ch = (tid & 3) * 16;
            const float* src = x + ((size_t)(b*CIN + c0 + c_l))*HW + hw0 + ch;
            float4 v0 = *(const float4*)(src + 0);
            float4 v1 = *(const float4*)(src + 4);
            float4 v2 = *(const float4*)(src + 8);
            float4 v3 = *(const float4*)(src + 12);
            *(float4*)&t[c_l][ch + 0]  = v0;
            *(float4*)&t[c_l][ch + 4]  = v1;
            *(float4*)&t[c_l][ch + 8]  = v2;
            *(float4*)&t[c_l][ch + 12] = v3;
        }
        __syncthreads();
        {
            const int hw_l = tid >> 2, cc = (tid & 3) * 16;
            float* dst = xt + ((size_t)(b*HW + hw0 + hw_l))*CIN + c0 + cc;
            #pragma unroll
            for (int q = 0; q < 4; ++q) {
                float4 o;
                o.x = t[cc + q*4 + 0][hw_l];
                o.y = t[cc + q*4 + 1][hw_l];
                o.z = t[cc + q*4 + 2][hw_l];
                o.w = t[cc + q*4 + 3][hw_l];
                *(float4*)(dst + q*4) = o;
            }
        }
    } else {
        const int id = (blockIdx.x - KA_NT)*256 + tid;
        if (id < COUT*KG) {
            int m = id / KG, kg = id % KG;
            int k = kg >> 8, i = kg & 255;
            float f = wconv[(m*CIN + i)*9 + k];
            int kt = kg >> 6, kk = kg & 63;
            _Float16 h = (_Float16)f;
            Ah[kt*16384 + m*64 + (kk ^ ((m & 7) << 3))] = __builtin_bit_cast(unsigned short, h);
        } else if (id < COUT*KG + 32*KG) {
            int id2 = id - COUT*KG;
            int m = id2 / KG, kg = id2 % KG;
            int k = kg >> 8, i = kg & 255;
            float f = (m < 18) ? woff[(m*CIN + i)*9 + k] : 0.f;
            int kt = kg >> 6, kk = kg & 63;
            _Float16 h = (_Float16)f;
            A0h[kt*2048 + m*64 + (kk ^ ((m & 7) << 3))] = __builtin_bit_cast(unsigned short, h);
        } else if (id < COUT*KG + 32*KG + 256) {
            int c = id - (COUT*KG + 32*KG);
            float inv = g[c] / sqrtf(rv[c] + 1e-5f);
            scale[c] = inv;
            shift[c] = be[c] - rm[c]*inv;
        }
    }
}

// ---------------------------------------------------------------------------
// K1: offset conv thin MFMA GEMM, full K per block, direct stores (+bias).
// grid 392 = 8 xcd * 49; 256 thr (4 waves), BN=64, BK=64. Async A0 prefetch,
// B im2col dbuf, counted vmcnt. im2col loads unconditional (clamped+zeroed)
// so the per-wave vmcnt count is uniform.
// ---------------------------------------------------------------------------
__global__ __launch_bounds__(256, 4) void k1_offmfma(
    const float* __restrict__ xt, const ushortT* __restrict__ A0h_g,
    const float* __restrict__ b_off, float* __restrict__ off)
{
    __shared__ __align__(16) ushortT A0[32*64];      // 4 KB single-buffer
    __shared__ __align__(16) ushortT Bh[2][64*64];   // 2 x 8 KB

    const int tid = threadIdx.x;
    const int x8 = blockIdx.x & 7;        // xcd == image
    const int lt = blockIdx.x >> 3;       // [0,49)
    const int bn0 = (x8*49 + lt) * 64;

    const int wv = tid >> 6, lane = tid & 63;
    const int l16 = lane & 15, lq = lane >> 4;
    const int px_l = tid >> 2, g2 = tid & 3;

    const int hw = lt*64 + px_l;          // pixel within image
    const int h = hw / WW, w = hw % WW;

    f32x4 acc[2] = {};
    float4 iv0, iv1, iv2, iv3;

    #define K1_IM2COL(ktg_) do {                                               \
        const int tap_ = (ktg_) >> 2, ic_ = (ktg_) & 3;                        \
        const int ky_ = tap_ / 3 - 1, kx_ = tap_ % 3 - 1;                      \
        const int hs_ = h + ky_, ws_ = w + kx_;                                \
        const bool valid_ = (hs_ >= 0 && hs_ < HH && ws_ >= 0 && ws_ < WW);    \
        const int hc_ = min(max(hs_, 0), HH-1), wc_ = min(max(ws_, 0), WW-1);  \
        const float* p_ = xt + ((size_t)(x8*HW + hc_*WW + wc_))*CIN + ic_*64 + g2*16; \
        iv0 = *(const float4*)(p_ + 0);  iv1 = *(const float4*)(p_ + 4);       \
        iv2 = *(const float4*)(p_ + 8);  iv3 = *(const float4*)(p_ + 12);      \
        if (!valid_) {                                                         \
            iv0 = iv1 = iv2 = iv3 = make_float4(0.f, 0.f, 0.f, 0.f);           \
        }                                                                      \
    } while (0)

    #define K1_PACK(buf_) do {                                                 \
        uint4 h0_, h1_;                                                        \
        h0_.x = packh2(iv0.x, iv0.y); h0_.y = packh2(iv0.z, iv0.w);            \
        h0_.z = packh2(iv1.x, iv1.y); h0_.w = packh2(iv1.z, iv1.w);            \
        h1_.x = packh2(iv2.x, iv2.y); h1_.y = packh2(iv2.z, iv2.w);            \
        h1_.z = packh2(iv3.x, iv3.y); h1_.w = packh2(iv3.z, iv3.w);            \
        const int base_ = g2 * 16;                                             \
        *(uint4*)&Bh[buf_][px_l*64 + ((base_ + 0) ^ ((px_l & 7) << 3))] = h0_; \
        *(uint4*)&Bh[buf_][px_l*64 + ((base_ + 8) ^ ((px_l & 7) << 3))] = h1_; \
    } while (0)

    #define K1_ISSUE_A0(ktg_)                                                  \
        __builtin_amdgcn_global_load_lds(                                      \
            (const __attribute__((address_space(1))) unsigned*)((const char*)A0h_g + (ktg_)*4096 + tid*16), \
            (__attribute__((address_space(3))) unsigned*)((char*)A0 + wv*1024), 16, 0, 0)

    // prologue
    K1_IM2COL(0);
    K1_ISSUE_A0(0);
    K1_PACK(0);                           // waits im2col loads, A0 stays in flight
    asm volatile("s_waitcnt lgkmcnt(0)" ::: "memory");
    __builtin_amdgcn_s_barrier();

    for (int t = 0; t < NKT; ++t) {
        const int cur = t & 1;
        if (t + 1 < NKT) {
            K1_IM2COL(t + 1);             // 4 loads, newest
            asm volatile("s_waitcnt vmcnt(4)" ::: "memory");   // retire A0(t)
        } else {
            asm volatile("s_waitcnt vmcnt(0)" ::: "memory");
        }
        __builtin_amdgcn_s_barrier();     // A0(t) + B[cur] ready for all waves
        __builtin_amdgcn_sched_barrier(0);
        {
            __builtin_amdgcn_s_setprio(1);
            #pragma unroll
            for (int ks = 0; ks < 2; ++ks) {
                const int kk0 = ks*32 + lq*8;
                const int m0 = l16, m1 = 16 + l16;
                f16x8 a0 = lds_ldh8(&A0[m0*64 + (kk0 ^ ((m0 & 7) << 3))]);
                f16x8 a1 = lds_ldh8(&A0[m1*64 + (kk0 ^ ((m1 & 7) << 3))]);
                const int n = wv*16 + l16;
                f16x8 b0 = lds_ldh8(&Bh[cur][n*64 + (kk0 ^ ((n & 7) << 3))]);
                acc[0] = __builtin_amdgcn_mfma_f32_16x16x32_f16(a0, b0, acc[0], 0, 0, 0);
                acc[1] = __builtin_amdgcn_mfma_f32_16x16x32_f16(a1, b0, acc[1], 0, 0, 0);
            }
            __builtin_amdgcn_s_setprio(0);
        }
        if (t + 1 < NKT) K1_PACK(cur ^ 1);
        asm volatile("s_waitcnt lgkmcnt(0)" ::: "memory");
        __builtin_amdgcn_s_barrier();     // MFMA done (A0 free), B[nxt] visible
        if (t + 1 < NKT) K1_ISSUE_A0(t + 1);
    }

    const int hw2 = lt*64 + wv*16 + l16;
    #pragma unroll
    for (int mf = 0; mf < 2; ++mf) {
        #pragma unroll
        for (int r = 0; r < 4; ++r) {
            const int m = mf*16 + lq*4 + r;
            if (m < 18)
                off[((size_t)x8*18 + m)*HW + hw2] = acc[mf][r] + b_off[m];
        }
    }
    #undef K1_IM2COL
    #undef K1_PACK
    #undef K1_ISSUE_A0
}

// ---------------------------------------------------------------------------
// K3: pipelined fused gather + fp16 MFMA (A single / B hi+lo) + BN + ReLU.
// grid 392 = 8 xcd * 49 (image per XCD); 512 thr; BM=256, BN=64, BK=64.
// Async A prefetch (global_load_lds, counted vmcnt(8)), B dbuf, inline META.
// ---------------------------------------------------------------------------
__global__ __launch_bounds__(512, 4) void k3_main(
    const float* __restrict__ xt, const float* __restrict__ off_g,
    const ushortT* __restrict__ Ah_g, const float* __restrict__ scale_g,
    const float* __restrict__ shift_g, float* __restrict__ out)
{
    __shared__ __align__(16) ushortT Ah_t[256*64];     // 32 KB single-buffer
    __shared__ __align__(16) ushortT Bh_t[2][64*64];   // 2 x 8 KB
    __shared__ __align__(16) ushortT Bl_t[2][64*64];   // 2 x 8 KB
    __shared__ float s_scale[256], s_shift[256];

    const int tid = threadIdx.x;
    const int bimg = blockIdx.x & 7;                  // xcd == image
    const int lt   = blockIdx.x >> 3;                 // [0,49)
    if (tid < 256) { s_scale[tid] = scale_g[tid]; s_shift[tid] = shift_g[tid]; }

    const int wv = tid >> 6, lane = tid & 63;
    const int l16 = lane & 15, lq = lane >> 4;
    const int mbase = (wv >> 1) * 64;
    const int nbase = (wv & 1) * 32;
    const int px_l = tid >> 3, g = tid & 7;
    const int hwp  = lt*64 + px_l;                    // pixel within image
    const int hp   = hwp / WW, wp = hwp % WW;

    int   mi[4];
    float mwv[4];
    f32x4 Gc[4][2];
    f32x4 acc[4][2] = {};

    #define META(tap_) do {                                                    \
        float dy_ = off_g[((size_t)bimg*18 + 2*(tap_)    )*HW + hwp];          \
        float dx_ = off_g[((size_t)bimg*18 + 2*(tap_) + 1)*HW + hwp];          \
        float py_ = (float)(hp - 1 + ((tap_) / 3)) + dy_;                      \
        float px_ = (float)(wp - 1 + ((tap_) % 3)) + dx_;                      \
        py_ = fminf(fmaxf(py_, -30000.f), 30000.f);                            \
        px_ = fminf(fmaxf(px_, -30000.f), 30000.f);                            \
        float y0f_ = floorf(py_), x0f_ = floorf(px_);                          \
        int y0_ = (int)y0f_, x0_ = (int)x0f_;                                  \
        float ly_ = py_ - y0f_, lx_ = px_ - x0f_;                              \
        float wy0_ = 1.f - ly_, wx0_ = 1.f - lx_;                              \
        _Pragma("unroll")                                                      \
        for (int c_ = 0; c_ < 4; ++c_) {                                       \
            int yi_ = y0_ + (c_ >> 1), xi_ = x0_ + (c_ & 1);                   \
            bool v_ = (yi_ >= 0) && (yi_ < HH) && (xi_ >= 0) && (xi_ < WW);    \
            int yc_ = min(max(yi_, 0), HH-1), xc_ = min(max(xi_, 0), WW-1);    \
            mi[c_] = (bimg*HW + yc_*WW + xc_)*CIN;                             \
            float wy_ = (c_ >> 1) ? ly_ : wy0_;                                \
            float wx_ = (c_ & 1) ? lx_ : wx0_;                                 \
            mwv[c_] = v_ ? wy_*wx_ : 0.f;                                      \
        }                                                                      \
    } while (0)

    #define ISSUE_GATHER(j_) do {                                              \
        const float* base_ = xt + ((j_) & 3)*64 + g*8;                         \
        _Pragma("unroll")                                                      \
        for (int c_ = 0; c_ < 4; ++c_) {                                       \
            const float* p_ = base_ + mi[c_];                                  \
            Gc[c_][0] = *(const f32x4*)p_;                                     \
            Gc[c_][1] = *(const f32x4*)(p_ + 4);                               \
        }                                                                      \
    } while (0)

    #define BLEND_WRITE(buf_) do {                                             \
        float v_[8];                                                           \
        _Pragma("unroll")                                                      \
        for (int q_ = 0; q_ < 4; ++q_) {                                       \
            v_[q_]   = mwv[0]*Gc[0][0][q_] + mwv[1]*Gc[1][0][q_]               \
                     + mwv[2]*Gc[2][0][q_] + mwv[3]*Gc[3][0][q_];              \
            v_[4+q_] = mwv[0]*Gc[0][1][q_] + mwv[1]*Gc[1][1][q_]               \
                     + mwv[2]*Gc[2][1][q_] + mwv[3]*Gc[3][1][q_];              \
        }                                                                      \
        uint4 hi_, lo_;                                                        \
        float r_[8];                                                           \
        _Pragma("unroll")                                                      \
        for (int q_ = 0; q_ < 8; ++q_) {                                       \
            _Float16 hh_ = (_Float16)v_[q_];                                   \
            r_[q_] = v_[q_] - (float)hh_;                                      \
        }                                                                      \
        hi_.x = packh2(v_[0], v_[1]); hi_.y = packh2(v_[2], v_[3]);            \
        hi_.z = packh2(v_[4], v_[5]); hi_.w = packh2(v_[6], v_[7]);            \
        lo_.x = packh2(r_[0], r_[1]); lo_.y = packh2(r_[2], r_[3]);            \
        lo_.z = packh2(r_[4], r_[5]); lo_.w = packh2(r_[6], r_[7]);            \
        const int idx_ = px_l*64 + ((g*8) ^ ((px_l & 7) << 3));                \
        *(uint4*)&Bh_t[buf_][idx_] = hi_;                                      \
        *(uint4*)&Bl_t[buf_][idx_] = lo_;                                      \
    } while (0)

    #define ISSUE_A(j_) do {                                                   \
        const char* gs_ = (const char*)Ah_g + (size_t)(j_)*32768;              \
        _Pragma("unroll")                                                      \
        for (int it_ = 0; it_ < 4; ++it_)                                      \
            __builtin_amdgcn_global_load_lds(                                  \
                (const __attribute__((address_space(1))) unsigned*)(gs_ + it_*8192 + tid*16), \
                (__attribute__((address_space(3))) unsigned*)((char*)Ah_t + it_*8192 + wv*1024), \
                16, 0, 0);                                                     \
    } while (0)

    #define MFMA_PHASE(cur_) do {                                              \
        __builtin_amdgcn_s_setprio(1);                                         \
        _Pragma("unroll")                                                      \
        for (int ks_ = 0; ks_ < 2; ++ks_) {                                    \
            const int kk0_ = ks_*32 + lq*8;                                    \
            f16x8 a_[4], bh_[2], bl_[2];                                       \
            _Pragma("unroll")                                                  \
            for (int mf_ = 0; mf_ < 4; ++mf_) {                                \
                const int m_ = mbase + mf_*16 + l16;                           \
                a_[mf_] = lds_ldh8(&Ah_t[m_*64 + (kk0_ ^ ((m_ & 7) << 3))]);   \
            }                                                                  \
            _Pragma("unroll")                                                  \
            for (int nf_ = 0; nf_ < 2; ++nf_) {                                \
                const int n_ = nbase + nf_*16 + l16;                           \
                const int ix_ = n_*64 + (kk0_ ^ ((n_ & 7) << 3));              \
                bh_[nf_] = lds_ldh8(&Bh_t[cur_][ix_]);                         \
                bl_[nf_] = lds_ldh8(&Bl_t[cur_][ix_]);                         \
            }                                                                  \
            _Pragma("unroll")                                                  \
            for (int mf_ = 0; mf_ < 4; ++mf_) {                                \
                _Pragma("unroll")                                              \
                for (int nf_ = 0; nf_ < 2; ++nf_) {                            \
                    acc[mf_][nf_] = __builtin_amdgcn_mfma_f32_16x16x32_f16(a_[mf_], bh_[nf_], acc[mf_][nf_], 0, 0, 0); \
                    acc[mf_][nf_] = __builtin_amdgcn_mfma_f32_16x16x32_f16(a_[mf_], bl_[nf_], acc[mf_][nf_], 0, 0, 0); \
                }                                                              \
            }                                                                  \
        }                                                                      \
        __builtin_amdgcn_s_setprio(0);                                         \
    } while (0)

    // ---- prologue: tile 0 ----
    META(0);
    ISSUE_GATHER(0);
    ISSUE_A(0);                          // A(0) in flight behind the gathers
    BLEND_WRITE(0);                      // waits exactly the 8 gather loads
    asm volatile("s_waitcnt lgkmcnt(0)" ::: "memory");
    __builtin_amdgcn_s_barrier();        // B[0] visible; A(0) still flying

    for (int kt = 0; kt < NKT; ++kt) {
        const int cur = kt & 1;
        if (kt + 1 < NKT) {
            if (((kt + 1) & 3) == 0) META((kt + 1) >> 2);
            ISSUE_GATHER(kt + 1);        // 8 loads, newest in stream
            asm volatile("s_waitcnt vmcnt(8)" ::: "memory");  // retire A(kt)+META
        } else {
            asm volatile("s_waitcnt vmcnt(0)" ::: "memory");
        }
        __builtin_amdgcn_s_barrier();    // all waves' A(kt) landed; B[cur] ready
        __builtin_amdgcn_sched_barrier(0);
        MFMA_PHASE(cur);
        if (kt + 1 < NKT) BLEND_WRITE(cur ^ 1);
        asm volatile("s_waitcnt lgkmcnt(0)" ::: "memory");
        __builtin_amdgcn_s_barrier();    // MFMA(kt) done (A free); B[nxt] visible
        if (kt + 1 < NKT) ISSUE_A(kt + 1);
    }

    // ---- epilogue: BN + ReLU + store ----
    const int hwb = lt * 64;
    #pragma unroll
    for (int mf = 0; mf < 4; ++mf) {
        #pragma unroll
        for (int nf = 0; nf < 2; ++nf) {
            const int hwloc = hwb + nbase + nf*16 + l16;
            const int m0 = mbase + mf*16 + lq*4;
            float* op = out + ((size_t)bimg*COUT + m0)*HW + hwloc;
            const f32x4 v = acc[mf][nf];
            #pragma unroll
            for (int r = 0; r < 4; ++r) {
                float val = fmaxf(v[r]*s_scale[m0 + r] + s_shift[m0 + r], 0.f);
                op[(size_t)r*HW] = val;
            }
        }
    }
    #undef META
    #undef ISSUE_GATHER
    #undef BLEND_WRITE
    #undef ISSUE_A
    #undef MFMA_PHASE
}

// ---------------------------------------------------------------------------
extern "C" void kernel_launch(void* const* d_in, const int* in_sizes, int n_in,
                              void* d_out, int out_size, void* d_ws, size_t ws_size,
                              hipStream_t stream)
{
    const float* x      = (const float*)d_in[0];
    const float* w_off  = (const float*)d_in[1];
    const float* b_off  = (const float*)d_in[2];
    const float* w_conv = (const float*)d_in[3];
    const float* gamma  = (const float*)d_in[4];
    const float* beta   = (const float*)d_in[5];
    const float* rmean  = (const float*)d_in[6];
    const float* rvar   = (const float*)d_in[7];
    float* out = (float*)d_out;
    char* ws = (char*)d_ws;

    // workspace layout (bytes), total ~28.9 MB
    float*   xt    = (float*)(ws + 0);           // 25690112 B
    float*   off   = (float*)(ws + 25690112);    //  1806336 B
    ushortT* Ah    = (ushortT*)(ws + 27496448);  //  1179648 B
    ushortT* A0h   = (ushortT*)(ws + 28676096);  //   147456 B
    float*   scale = (float*)(ws + 28823552);    //     1024 B
    float*   shift = (float*)(ws + 28824576);    //     1024 B

    hipLaunchKernelGGL(kA_prep, dim3(KA_NT + KA_NW), dim3(256), 0, stream,
                       x, xt, w_conv, w_off, gamma, beta, rmean, rvar,
                       Ah, A0h, scale, shift);
    hipLaunchKernelGGL(k1_offmfma, dim3(392), dim3(256), 0, stream, xt, A0h, b_off, off);
    hipLaunchKernelGGL(k3_main, dim3(392), dim3(512), 0, stream,
                       xt, off, Ah, scale, shift, out);
}